// Round 1
// 379.525 us; speedup vs baseline: 1.0738x; 1.0738x over previous
//
#include <hip/hip_runtime.h>
#include <stdint.h>
#include <stddef.h>

#define LN_EPS 1e-5f

typedef __bf16 bf16;
typedef __bf16 bf16x8 __attribute__((ext_vector_type(8)));
typedef __bf16 bf16x4 __attribute__((ext_vector_type(4)));
typedef float f32x4 __attribute__((ext_vector_type(4)));

// async global->LDS, 16B per lane. LDS dest must be wave-uniform base + lane*16.
#define GL16(gp, lp)                                                                   \
  __builtin_amdgcn_global_load_lds((__attribute__((address_space(1))) uint32_t*)(gp),  \
                                   (__attribute__((address_space(3))) uint32_t*)(lp),  \
                                   16, 0, 0)

#define SBAR   asm volatile("s_barrier" ::: "memory")
#define LGK0   asm volatile("s_waitcnt lgkmcnt(0)" ::: "memory")
#define VMW(N) asm volatile("s_waitcnt vmcnt(" #N ")" ::: "memory")
#define NOWAIT ((void)0)

// ---------------------------------------------------------------------------
// single fp32 -> bf16 convert kernel for all three tensors (one launch)
// ---------------------------------------------------------------------------
#define XV4   6291456           // x:      25,165,824 f32 / 4
#define WQV4  442368            // w_qkv:   1,769,472 f32 / 4
#define WPV4  147456            // w_proj:    589,824 f32 / 4
__global__ __launch_bounds__(256) void cvt_all(const float* __restrict__ x,
                                               const float* __restrict__ wq,
                                               const float* __restrict__ wp,
                                               bf16* __restrict__ xb,
                                               bf16* __restrict__ wqb,
                                               bf16* __restrict__ wpb) {
  int i = blockIdx.x * 256 + threadIdx.x;
  const float* src; bf16* dst; int off;
  if (i < XV4)              { src = x;  dst = xb;  off = i; }
  else if (i < XV4 + WQV4)  { src = wq; dst = wqb; off = i - XV4; }
  else                      { src = wp; dst = wpb; off = i - (XV4 + WQV4); }
  const float4 v = ((const float4*)src)[off];
  bf16x4 o;
  o[0] = (bf16)v.x; o[1] = (bf16)v.y; o[2] = (bf16)v.z; o[3] = (bf16)v.w;
  ((bf16x4*)dst)[off] = o;
}

// ---------------------------------------------------------------------------
// 256x256-tile, BK=64, 8-wave (2Mx4N), 8-phase GEMM core with counted vmcnt.
// K = 768 (12 K-tiles). LDS: per operand a 4-slot ring of K-half units
// (256 rows x 32 cols bf16 = 16KB). slot(T,kh) = (2T+kh)&3.
// Swizzle: LDS(r, chunk) holds global (r, chunk ^ ((r>>1)&3)) [16B chunks],
// applied via pre-swizzled global source (GL16 dest stays linear) and the
// matching XOR on ds_read addresses -> all ds_read_b128 are 2-way = free.
// Per phase (kh, mh): 4 A-frag reads (+4 B reads on mh==0), 1 unit staged,
// s_barrier, lgkmcnt(0), 16 MFMA (setprio 1), [vmcnt ckpt], s_barrier.
// vmcnt(8) checkpoints every 2 phases complete everything issued >=4 units
// ago, which is exactly what the next K-half reads. Tail drains 8->4->0.
// ---------------------------------------------------------------------------
#define STAGE_A(T, KH, SLOT) do {                      \
    GL16(pA0 + (T)*64 + (KH)*32, dA + (SLOT)*8192);    \
    GL16(pA1 + (T)*64 + (KH)*32, dA + (SLOT)*8192 + 4096); } while (0)

#define STAGE_B(T, KH, SLOT) do {                      \
    GL16(pB0 + (T)*64 + (KH)*32, dB + (SLOT)*8192);    \
    GL16(pB1 + (T)*64 + (KH)*32, dB + (SLOT)*8192 + 4096); } while (0)

#define PHASE(SLOT, MH, RB, STG, WAIT) do {                                         \
    if (RB) {                                                                       \
      _Pragma("unroll") for (int n = 0; n < 4; ++n)                                 \
        bF[n] = *(const bf16x8*)(ldsB + (SLOT)*8192 + (rB + n*16)*32 + colE);       \
    }                                                                               \
    _Pragma("unroll") for (int m = 0; m < 4; ++m)                                   \
      aF[m] = *(const bf16x8*)(ldsA + (SLOT)*8192 + (rA + (MH)*64 + m*16)*32 + colE); \
    STG;                                                                            \
    SBAR;                                                                           \
    LGK0;                                                                           \
    __builtin_amdgcn_sched_barrier(0);                                              \
    __builtin_amdgcn_s_setprio(1);                                                  \
    _Pragma("unroll") for (int m = 0; m < 4; ++m)                                   \
      _Pragma("unroll") for (int n = 0; n < 4; ++n)                                 \
        acc[(MH)*4 + m][n] =                                                        \
            __builtin_amdgcn_mfma_f32_16x16x32_bf16(aF[m], bF[n],                   \
                                                    acc[(MH)*4 + m][n], 0, 0, 0);   \
    __builtin_amdgcn_s_setprio(0);                                                  \
    WAIT;                                                                           \
    SBAR;                                                                           \
  } while (0)

#define TILE(SB, ST1, ST2, ST3, ST4, W2, W4) do { \
    PHASE((SB),     0, true,  ST1, NOWAIT);       \
    PHASE((SB),     1, false, ST2, W2);           \
    PHASE((SB) + 1, 0, true,  ST3, NOWAIT);       \
    PHASE((SB) + 1, 1, false, ST4, W4);           \
  } while (0)

__device__ __forceinline__ void gemm256(const bf16* pA0, const bf16* pA1,
                                        const bf16* pB0, const bf16* pB1,
                                        bf16* sh, f32x4 acc[8][4]) {
  const int tid  = threadIdx.x;
  const int lane = tid & 63;
  const int wave = tid >> 6;
  const int wm   = wave >> 2;          // 0..1
  const int wn   = wave & 3;           // 0..3
  const int l16  = lane & 15;
  // per-lane read column byte, swizzled: (qg*16B) ^ (((r>>1)&3)<<4), r≡l16 mod 16
  const int colE = ((((lane >> 4) * 16) ^ (((l16 >> 1) & 3) << 4)) >> 1);
  bf16* const ldsA = sh;               // 4 slots x 8192 elems
  bf16* const ldsB = sh + 32768;
  bf16* const dA   = ldsA + tid * 8;   // + slot*8192 + pass*4096 (wave-uniform+lane*16B)
  bf16* const dB   = ldsB + tid * 8;
  const int rA = wm * 128 + l16;       // + mh*64 + m*16
  const int rB = wn * 64 + l16;        // + n*16
  bf16x8 aF[4], bF[4];

  // prologue: units [0A0,0B0,0A1,0B1,1A0,1B0]; vmcnt(8) -> 0A0,0B0 resident
  STAGE_A(0, 0, 0); STAGE_B(0, 0, 0);
  STAGE_A(0, 1, 1); STAGE_B(0, 1, 1);
  STAGE_A(1, 0, 2); STAGE_B(1, 0, 2);
  VMW(8);
  SBAR;

  for (int T = 0; T < 10; T += 2) {
    TILE(0, STAGE_A(T+1,1,3), STAGE_B(T+1,1,3), STAGE_A(T+2,0,0), STAGE_B(T+2,0,0), VMW(8), VMW(8));
    TILE(2, STAGE_A(T+2,1,1), STAGE_B(T+2,1,1), STAGE_A(T+3,0,2), STAGE_B(T+3,0,2), VMW(8), VMW(8));
  }
  // T=10: only tile-11 k1 stages remain; T=11: none. Drain 8 -> 4 -> 0.
  TILE(0, STAGE_A(11,1,3), STAGE_B(11,1,3), NOWAIT, NOWAIT, VMW(8), VMW(4));
  TILE(2, NOWAIT, NOWAIT, NOWAIT, NOWAIT, VMW(0), NOWAIT);

  asm volatile("s_waitcnt vmcnt(0) lgkmcnt(0)" ::: "memory");
  __syncthreads();
}

// ---------------------------------------------------------------------------
// Pass 1: k/v GEMM + fused p2-weighted k*v reduction. Grid (6 head-pairs, 128).
// Block: C[256 n-rows][256 cols], cols = [k_h0 | v_h0 | k_h1 | v_h1] spliced
// from w_qkv rows per 64-row segment. Epilogue: bf16 spill to LDS (XOR
// bank-swizzle), reduce sum_n p2*k*v -> partials[mblk][h][64].
// ---------------------------------------------------------------------------
__global__ __launch_bounds__(512, 2) void kv_gemm_reduce(const bf16* __restrict__ A,
                                                         const bf16* __restrict__ B,
                                                         const float* __restrict__ p2,
                                                         float* __restrict__ partials) {
  __shared__ __align__(16) bf16 sh[65536];     // 128 KB staging, aliased by spill
  __shared__ float red[4][2][64];

  int lin = blockIdx.y * 6 + blockIdx.x;       // 768 blocks, XCD-bijective swizzle
  lin = (lin & 7) * 96 + (lin >> 3);
  const int hh   = lin % 6;
  const int mblk = lin / 6;
  const int m0   = mblk * 256;
  const int h0   = hh * 2;

  const int tid = threadIdx.x;
  const int rr  = tid >> 2;                                  // 0..127
  const int ck  = ((tid & 3) ^ ((tid >> 3) & 3)) * 8;        // pre-swizzled src col
  const bf16* pA0 = A + (size_t)(m0 + rr) * 768 + ck;
  const bf16* pA1 = pA0 + (size_t)128 * 768;
  // B-tile row r -> w_qkv row: seg = r>>6; 768 + (seg&1)*768 + (h0+(seg>>1))*64 + r%64
  const int r1 = 128 + rr;
  const int wr0 = 768 + (((rr >> 6) & 1) * 768) + (h0 + (rr >> 7)) * 64 + (rr & 63);
  const int wr1 = 768 + (((r1 >> 6) & 1) * 768) + (h0 + (r1 >> 7)) * 64 + (r1 & 63);
  const bf16* pB0 = B + (size_t)wr0 * 768 + ck;
  const bf16* pB1 = B + (size_t)wr1 * 768 + ck;

  f32x4 acc[8][4] = {};
  gemm256(pA0, pA1, pB0, pB1, sh, acc);

  // ---- spill C as bf16 into sh[256][256], col ^= ((row>>2)&3)<<4 (2-way free)
  const int lane = tid & 63, wave = tid >> 6;
  const int wm = wave >> 2, wn = wave & 3, l16 = lane & 15;
  const int crow0 = wm * 128 + (lane >> 4) * 4;
  const int ccol0 = wn * 64 + l16;
#pragma unroll
  for (int mi = 0; mi < 8; ++mi)
#pragma unroll
    for (int ni = 0; ni < 4; ++ni)
#pragma unroll
      for (int r = 0; r < 4; ++r) {
        const int row = crow0 + mi * 16 + r;
        const int col = ccol0 + ni * 16;
        sh[row * 256 + (col ^ (((row >> 2) & 3) << 4))] = (bf16)acc[mi][ni][r];
      }
  __syncthreads();

  // ---- reduce 256 rows: thread = (chunk 0..3, hl 0..1, d 0..63), 64 rows each
  const int chunk = tid >> 7, hl = (tid >> 6) & 1, d = tid & 63;
  const float* pw = p2 + (size_t)(h0 + hl) * 4096 + (m0 & 4095) + chunk * 64;
  float s = 0.f;
#pragma unroll 8
  for (int n = 0; n < 64; ++n) {
    const int row = chunk * 64 + n;
    const int x = ((row >> 2) & 3) << 4;
    const float kk = (float)sh[row * 256 + ((hl * 128 + d) ^ x)];
    const float vv = (float)sh[row * 256 + ((hl * 128 + 64 + d) ^ x)];
    s += pw[n] * kk * vv;
  }
  red[chunk][hl][d] = s;
  __syncthreads();
  if (tid < 128) {
    const int hx = tid >> 6, dd = tid & 63;
    partials[((size_t)mblk * 12 + h0 + hx) * 64 + dd] =
        red[0][hx][dd] + red[1][hx][dd] + red[2][hx][dd] + red[3][hx][dd];
  }
}

// ---------------------------------------------------------------------------
// Stage 2: sum the 16 per-mblk partials of each batch, then LayerNorm over d.
// grid (12 h, 8 b); 64 threads, d = lane.
// ---------------------------------------------------------------------------
__global__ __launch_bounds__(64) void mod_reduce_ln(const float* __restrict__ partials,
                                                    const float* __restrict__ gamma,
                                                    const float* __restrict__ beta,
                                                    float* __restrict__ mod) {
  const int h = blockIdx.x, b = blockIdx.y;
  const int d = threadIdx.x;

  const float* p = partials + ((size_t)(b * 16) * 12 + h) * 64 + d;
  float s = 0.f;
#pragma unroll
  for (int mb = 0; mb < 16; ++mb) s += p[(size_t)mb * 12 * 64];

  float sum = s, sumsq = s * s;
#pragma unroll
  for (int o = 32; o > 0; o >>= 1) {
    sum   += __shfl_xor(sum, o);
    sumsq += __shfl_xor(sumsq, o);
  }
  const float mu  = sum * (1.f / 64.f);
  const float var = sumsq * (1.f / 64.f) - mu * mu;
  const float r   = rsqrtf(var + LN_EPS);
  mod[(b * 12 + h) * 64 + d] = (s - mu) * r * gamma[d] + beta[d];
}

// ---------------------------------------------------------------------------
// Pass 2: q GEMM + fused modulation. Grid (3 nblk, 128 mblk).
// amod[m, c] = q[m, c] * p1[h(c), n(m)] * mod[b(m), c]  (bf16 out)
// ---------------------------------------------------------------------------
__global__ __launch_bounds__(512, 2) void q_gemm_mod(const bf16* __restrict__ A,
                                                     const bf16* __restrict__ B,
                                                     const float* __restrict__ p1,
                                                     const float* __restrict__ mod,
                                                     bf16* __restrict__ amod) {
  __shared__ __align__(16) bf16 sh[65536];

  int lin = blockIdx.y * 3 + blockIdx.x;       // 384 blocks, XCD-bijective swizzle
  lin = (lin & 7) * 48 + (lin >> 3);
  const int n0 = (lin % 3) * 256;
  const int m0 = (lin / 3) * 256;

  const int tid = threadIdx.x;
  const int rr  = tid >> 2;
  const int ck  = ((tid & 3) ^ ((tid >> 3) & 3)) * 8;
  const bf16* pA0 = A + (size_t)(m0 + rr) * 768 + ck;
  const bf16* pA1 = pA0 + (size_t)128 * 768;
  const bf16* pB0 = B + (size_t)(n0 + rr) * 768 + ck;
  const bf16* pB1 = pB0 + (size_t)128 * 768;

  f32x4 acc[8][4] = {};
  gemm256(pA0, pA1, pB0, pB1, sh, acc);

  const int lane = tid & 63, wave = tid >> 6;
  const int wm = wave >> 2, wn = wave & 3, l16 = lane & 15;
  const int row0 = m0 + wm * 128 + (lane >> 4) * 4;
  const int col0 = n0 + wn * 64 + l16;
  const int b    = m0 >> 12;
  const int h    = (n0 >> 6) + wn;             // wave-uniform head

  float p1v[8][4];
#pragma unroll
  for (int mi = 0; mi < 8; ++mi)
#pragma unroll
    for (int r = 0; r < 4; ++r)
      p1v[mi][r] = p1[(size_t)h * 4096 + ((row0 + mi * 16 + r) & 4095)];
  float mv[4];
#pragma unroll
  for (int ni = 0; ni < 4; ++ni) mv[ni] = mod[b * 768 + col0 + ni * 16];

#pragma unroll
  for (int mi = 0; mi < 8; ++mi)
#pragma unroll
    for (int ni = 0; ni < 4; ++ni)
#pragma unroll
      for (int r = 0; r < 4; ++r)
        amod[(size_t)(row0 + mi * 16 + r) * 768 + col0 + ni * 16] =
            (bf16)(acc[mi][ni][r] * p1v[mi][r] * mv[ni]);
}

// ---------------------------------------------------------------------------
// Pass 3: out[32768,768] fp32 = amod @ w_proj_bf16^T + b_proj. Grid (3, 128).
// ---------------------------------------------------------------------------
__global__ __launch_bounds__(512, 2) void gemm_proj(const bf16* __restrict__ A,
                                                    const bf16* __restrict__ B,
                                                    const float* __restrict__ bias,
                                                    float* __restrict__ C) {
  __shared__ __align__(16) bf16 sh[65536];

  int lin = blockIdx.y * 3 + blockIdx.x;
  lin = (lin & 7) * 48 + (lin >> 3);
  const int n0 = (lin % 3) * 256;
  const int m0 = (lin / 3) * 256;

  const int tid = threadIdx.x;
  const int rr  = tid >> 2;
  const int ck  = ((tid & 3) ^ ((tid >> 3) & 3)) * 8;
  const bf16* pA0 = A + (size_t)(m0 + rr) * 768 + ck;
  const bf16* pA1 = pA0 + (size_t)128 * 768;
  const bf16* pB0 = B + (size_t)(n0 + rr) * 768 + ck;
  const bf16* pB1 = pB0 + (size_t)128 * 768;

  f32x4 acc[8][4] = {};
  gemm256(pA0, pA1, pB0, pB1, sh, acc);

  const int lane = tid & 63, wave = tid >> 6;
  const int wm = wave >> 2, wn = wave & 3, l16 = lane & 15;
  const int row0 = m0 + wm * 128 + (lane >> 4) * 4;
  const int col0 = n0 + wn * 64 + l16;
#pragma unroll
  for (int ni = 0; ni < 4; ++ni) {
    const int col = col0 + ni * 16;
    const float bv = bias[col];
#pragma unroll
    for (int mi = 0; mi < 8; ++mi)
#pragma unroll
      for (int r = 0; r < 4; ++r)
        C[(size_t)(row0 + mi * 16 + r) * 768 + col] = acc[mi][ni][r] + bv;
  }
}

// ---------------------------------------------------------------------------
extern "C" void kernel_launch(void* const* d_in, const int* in_sizes, int n_in,
                              void* d_out, int out_size, void* d_ws, size_t ws_size,
                              hipStream_t stream) {
  (void)in_sizes; (void)n_in; (void)out_size; (void)ws_size;

  const float* x      = (const float*)d_in[0];   // [8,4096,768]
  const float* w_qkv  = (const float*)d_in[1];   // [2304,768]
  const float* w_proj = (const float*)d_in[2];   // [768,768]
  const float* b_proj = (const float*)d_in[3];   // [768]
  const float* p1     = (const float*)d_in[4];   // [12,4096]
  const float* p2     = (const float*)d_in[5];   // [12,4096]
  const float* gamma  = (const float*)d_in[6];   // [64]
  const float* beta   = (const float*)d_in[7];   // [64]
  float* out = (float*)d_out;                    // [8,4096,768] fp32

  char* ws = (char*)d_ws;
  bf16*  xb       = (bf16*)(ws + 0);              // 50,331,648  x bf16 [32768,768]
  bf16*  wqb      = (bf16*)(ws + 50331648);       //  3,538,944  w_qkv bf16
  bf16*  wpb      = (bf16*)(ws + 53870592);       //  1,179,648  w_proj bf16
  bf16*  amod     = (bf16*)(ws + 55050240);       // 50,331,648  amod bf16 [32768,768]
  float* partials = (float*)(ws + 105381888);     //    393,216  [128][12][64] f32
  float* mod      = (float*)(ws + 106168320);     //     24,576  [8][12][64] f32

  // 1) all fp32 -> bf16 conversions in one launch (26,880 blocks exact)
  cvt_all<<<26880, 256, 0, stream>>>(x, w_qkv, w_proj, xb, wqb, wpb);

  // 2) k/v GEMM + fused p2*k*v reduction (k,v never written to HBM)
  kv_gemm_reduce<<<dim3(6, 128), 512, 0, stream>>>(xb, wqb, p2, partials);

  // 3) finish reduction + LayerNorm -> mod [8,12,64]
  mod_reduce_ln<<<dim3(12, 8), 64, 0, stream>>>(partials, gamma, beta, mod);

  // 4) q GEMM + fused p1/mod modulation -> amod bf16
  q_gemm_mod<<<dim3(3, 128), 512, 0, stream>>>(xb, wqb, p1, mod, amod);

  // 5) proj GEMM + bias -> out fp32
  gemm_proj<<<dim3(3, 128), 512, 0, stream>>>(amod, wpb, b_proj, out);
}

// Round 2
// 374.529 us; speedup vs baseline: 1.0881x; 1.0133x over previous
//
#include <hip/hip_runtime.h>
#include <stdint.h>
#include <stddef.h>

#define LN_EPS 1e-5f

typedef __bf16 bf16;
typedef __bf16 bf16x8 __attribute__((ext_vector_type(8)));
typedef __bf16 bf16x4 __attribute__((ext_vector_type(4)));
typedef float f32x4 __attribute__((ext_vector_type(4)));

// async global->LDS, 16B per lane. LDS dest must be wave-uniform base + lane*16.
#define GL16(gp, lp)                                                                   \
  __builtin_amdgcn_global_load_lds((__attribute__((address_space(1))) uint32_t*)(gp),  \
                                   (__attribute__((address_space(3))) uint32_t*)(lp),  \
                                   16, 0, 0)

#define SBAR   asm volatile("s_barrier" ::: "memory")
#define VMW(N) asm volatile("s_waitcnt vmcnt(" #N ")" ::: "memory")
#define LGK(N) asm volatile("s_waitcnt lgkmcnt(" #N ")" ::: "memory")
#define NOWAIT ((void)0)

// ---------------------------------------------------------------------------
// single fp32 -> bf16 convert kernel for all three tensors (one launch)
// ---------------------------------------------------------------------------
#define XV4   6291456           // x:      25,165,824 f32 / 4
#define WQV4  442368            // w_qkv:   1,769,472 f32 / 4
#define WPV4  147456            // w_proj:    589,824 f32 / 4
__global__ __launch_bounds__(256) void cvt_all(const float* __restrict__ x,
                                               const float* __restrict__ wq,
                                               const float* __restrict__ wp,
                                               bf16* __restrict__ xb,
                                               bf16* __restrict__ wqb,
                                               bf16* __restrict__ wpb) {
  int i = blockIdx.x * 256 + threadIdx.x;
  const float* src; bf16* dst; int off;
  if (i < XV4)              { src = x;  dst = xb;  off = i; }
  else if (i < XV4 + WQV4)  { src = wq; dst = wqb; off = i - XV4; }
  else                      { src = wp; dst = wpb; off = i - (XV4 + WQV4); }
  const float4 v = ((const float4*)src)[off];
  bf16x4 o;
  o[0] = (bf16)v.x; o[1] = (bf16)v.y; o[2] = (bf16)v.z; o[3] = (bf16)v.w;
  ((bf16x4*)dst)[off] = o;
}

// ---------------------------------------------------------------------------
// 256x256-tile, 8-wave (2Mx4N), software-pipelined GEMM core, K = 768.
// K-halves kh = 0..23 (32 wide). LDS: 4-slot rings per operand, slot = kh&3,
// unit = 256x32 bf16 = 16KB (2 GL16 lines). Staging: even(kh) stages A(kh+3),
// odd(kh) stages B(kh+3).  XOR swizzle (chunk ^ (row>>1)&3) via pre-swizzled
// global source + swizzled ds_read col -> conflict-free ds_read_b128.
//
// Cross-phase register pipeline (the r1->r2 change):
//  even(kh): issue 4 aF1 reads (slot kh) ; stage ; lgkmcnt(4) [completes the
//            8 pair-kh reads from odd(kh-1), keeps aF1 in flight] ; 16 MFMA ;
//            vmcnt(6) [youngest 3 units stay in flight => A/B(kh+1) complete] ;
//            s_barrier.
//  odd(kh):  issue 8 reads of pair kh+1 (now resident) ; stage ; lgkmcnt(8)
//            [completes aF1 only] ; 16 MFMA ; s_barrier.
// One barrier per phase. Wait ledger (prologue/tail) derived in comments below.
// ---------------------------------------------------------------------------
#define STAGE_A2(H, SL) do {                          \
    GL16(pA0 + (H)*32, dA + (SL)*8192);               \
    GL16(pA1 + (H)*32, dA + (SL)*8192 + 4096); } while (0)

#define STAGE_B2(H, SL) do {                          \
    GL16(pB0 + (H)*32, dB + (SL)*8192);               \
    GL16(pB1 + (H)*32, dB + (SL)*8192 + 4096); } while (0)

#define RD_B(DST, SL)                                                              \
    _Pragma("unroll") for (int n = 0; n < 4; ++n)                                  \
      DST[n] = *(const bf16x8*)(ldsB + (SL)*8192 + (rB + n*16)*32 + colE)

#define RD_A0(DST, SL)                                                             \
    _Pragma("unroll") for (int m = 0; m < 4; ++m)                                  \
      DST[m] = *(const bf16x8*)(ldsA + (SL)*8192 + (rA + m*16)*32 + colE)

#define RD_A1(SL)                                                                  \
    _Pragma("unroll") for (int m = 0; m < 4; ++m)                                  \
      af1[m] = *(const bf16x8*)(ldsA + (SL)*8192 + (rA + 64 + m*16)*32 + colE)

#define MM(AF, BF, MO)                                                             \
    _Pragma("unroll") for (int m = 0; m < 4; ++m)                                  \
      _Pragma("unroll") for (int n = 0; n < 4; ++n)                                \
        acc[(MO) + m][n] = __builtin_amdgcn_mfma_f32_16x16x32_bf16(                \
            AF[m], BF[n], acc[(MO) + m][n], 0, 0, 0)

#define EV_PHASE(SL, A0C, BFC, STG, WAITV) do {       \
    RD_A1(SL);                                        \
    STG;                                              \
    LGK(4);                                           \
    __builtin_amdgcn_sched_barrier(0);                \
    __builtin_amdgcn_s_setprio(1);                    \
    MM(A0C, BFC, 0);                                  \
    __builtin_amdgcn_s_setprio(0);                    \
    WAITV;                                            \
    SBAR;                                             \
  } while (0)

#define OD_PHASE(NSL, A0N, BFN, BFC, STG, LGKW) do {  \
    RD_B(BFN, NSL);                                   \
    RD_A0(A0N, NSL);                                  \
    STG;                                              \
    LGKW;                                             \
    __builtin_amdgcn_sched_barrier(0);                \
    __builtin_amdgcn_s_setprio(1);                    \
    MM(af1, BFC, 4);                                  \
    __builtin_amdgcn_s_setprio(0);                    \
    SBAR;                                             \
  } while (0)

__device__ __forceinline__ void gemm256(const bf16* pA0, const bf16* pA1,
                                        const bf16* pB0, const bf16* pB1,
                                        bf16* sh, f32x4 acc[8][4]) {
  const int tid  = threadIdx.x;
  const int lane = tid & 63;
  const int wave = tid >> 6;
  const int wm   = wave >> 2;          // 0..1
  const int wn   = wave & 3;           // 0..3
  const int l16  = lane & 15;
  // per-lane read column (bf16 elems), swizzled to match pre-swizzled staging
  const int colE = ((((lane >> 4) * 16) ^ (((l16 >> 1) & 3) << 4)) >> 1);
  bf16* const ldsA = sh;               // 4 slots x 8192 elems
  bf16* const ldsB = sh + 32768;
  bf16* const dA   = ldsA + tid * 8;   // wave-uniform base + lane*16B
  bf16* const dB   = ldsB + tid * 8;
  const int rA = wm * 128 + l16;       // + 64*mh + m*16
  const int rB = wn * 64 + l16;        // + n*16
  bf16x8 af0X[4], af0Y[4], af1[4], bfX[4], bfY[4];

  // prologue: stage units A0,B0,A1,B1,A2,B2 (12 loads).
  // VMW(8) leaves 4 units in flight -> A0,B0 complete. Barrier -> visible.
  STAGE_A2(0, 0); STAGE_B2(0, 0);
  STAGE_A2(1, 1); STAGE_B2(1, 1);
  STAGE_A2(2, 2); STAGE_B2(2, 2);
  VMW(8);
  SBAR;
  RD_B(bfX, 0);          // pair-0 prefetch ("phase -1")
  RD_A0(af0X, 0);

  for (int h4 = 0; h4 < 20; h4 += 4) {
    EV_PHASE(0, af0X, bfX, STAGE_A2(h4 + 3, 3), VMW(6));
    OD_PHASE(1, af0Y, bfY, bfX, STAGE_B2(h4 + 3, 3), LGK(8));
    EV_PHASE(1, af0Y, bfY, STAGE_A2(h4 + 4, 0), VMW(6));
    OD_PHASE(2, af0X, bfX, bfY, STAGE_B2(h4 + 4, 0), LGK(8));
    EV_PHASE(2, af0X, bfX, STAGE_A2(h4 + 5, 1), VMW(6));
    OD_PHASE(3, af0Y, bfY, bfX, STAGE_B2(h4 + 5, 1), LGK(8));
    EV_PHASE(3, af0Y, bfY, STAGE_A2(h4 + 6, 2), VMW(6));
    OD_PHASE(0, af0X, bfX, bfY, STAGE_B2(h4 + 6, 2), LGK(8));
  }
  // tail: kh = 20..23. Last stages: A23 at even(20), B23 at odd(20).
  // even(21): in-flight {A23,B23} + older {A22,B22} -> VMW(4) completes A22,B22
  //           (needed by odd(21)'s pair-22 prefetch).
  // even(22): VMW(0) completes A23,B23 (needed by odd(22)'s pair-23 prefetch).
  EV_PHASE(0, af0X, bfX, STAGE_A2(23, 3), VMW(6));
  OD_PHASE(1, af0Y, bfY, bfX, STAGE_B2(23, 3), LGK(8));
  EV_PHASE(1, af0Y, bfY, NOWAIT, VMW(4));
  OD_PHASE(2, af0X, bfX, bfY, NOWAIT, LGK(8));
  EV_PHASE(2, af0X, bfX, NOWAIT, VMW(0));
  OD_PHASE(3, af0Y, bfY, bfX, NOWAIT, LGK(8));
  EV_PHASE(3, af0Y, bfY, NOWAIT, NOWAIT);
  // final odd (kh=23): only af1's 4 reads outstanding
  LGK(0);
  __builtin_amdgcn_sched_barrier(0);
  __builtin_amdgcn_s_setprio(1);
  MM(af1, bfY, 4);
  __builtin_amdgcn_s_setprio(0);
  asm volatile("s_waitcnt vmcnt(0) lgkmcnt(0)" ::: "memory");
  __syncthreads();
}

// ---------------------------------------------------------------------------
// Pass 1: k/v GEMM + fused p2-weighted k*v reduction. Grid (6 head-pairs, 128).
// Block: C[256 n-rows][256 cols], cols = [k_h0 | v_h0 | k_h1 | v_h1] spliced
// from w_qkv rows per 64-row segment. Epilogue: TRANSPOSED bf16 spill
// shT[c][n] (stride 264 -> lane-bank delta 4 -> conflict-free b128 reads),
// b64-packed writes, vectorized reduce sum_n p2*k*v -> partials[mblk][h][64].
// ---------------------------------------------------------------------------
__global__ __launch_bounds__(512, 2) void kv_gemm_reduce(const bf16* __restrict__ A,
                                                         const bf16* __restrict__ B,
                                                         const float* __restrict__ p2,
                                                         float* __restrict__ partials) {
  __shared__ __align__(16) bf16 sh[256 * 264];   // 135,168 B; first 131,072 = staging
  __shared__ float red[4][2][64];

  int lin = blockIdx.y * 6 + blockIdx.x;       // 768 blocks, XCD-bijective swizzle
  lin = (lin & 7) * 96 + (lin >> 3);
  const int hh   = lin % 6;
  const int mblk = lin / 6;
  const int m0   = mblk * 256;
  const int h0   = hh * 2;

  const int tid = threadIdx.x;
  const int rr  = tid >> 2;                                  // 0..127
  const int ck  = ((tid & 3) ^ ((tid >> 3) & 3)) * 8;        // pre-swizzled src col
  const bf16* pA0 = A + (size_t)(m0 + rr) * 768 + ck;
  const bf16* pA1 = pA0 + (size_t)128 * 768;
  // B-tile row r -> w_qkv row: seg = r>>6; 768 + (seg&1)*768 + (h0+(seg>>1))*64 + r%64
  const int r1 = 128 + rr;
  const int wr0 = 768 + (((rr >> 6) & 1) * 768) + (h0 + (rr >> 7)) * 64 + (rr & 63);
  const int wr1 = 768 + (((r1 >> 6) & 1) * 768) + (h0 + (r1 >> 7)) * 64 + (r1 & 63);
  const bf16* pB0 = B + (size_t)wr0 * 768 + ck;
  const bf16* pB1 = B + (size_t)wr1 * 768 + ck;

  f32x4 acc[8][4] = {};
  gemm256(pA0, pA1, pB0, pB1, sh, acc);

  // ---- transposed spill: shT[c][n], stride 264 elems, b64-packed (4 rows/col)
  const int lane = tid & 63, wave = tid >> 6;
  const int wm = wave >> 2, wn = wave & 3, l16 = lane & 15;
  const int c0 = wn * 64 + l16;                 // + ni*16
  const int r0 = wm * 128 + (lane >> 4) * 4;    // + mi*16
#pragma unroll
  for (int ni = 0; ni < 4; ++ni)
#pragma unroll
    for (int mi = 0; mi < 8; ++mi) {
      bf16x4 pk;
      pk[0] = (bf16)acc[mi][ni][0]; pk[1] = (bf16)acc[mi][ni][1];
      pk[2] = (bf16)acc[mi][ni][2]; pk[3] = (bf16)acc[mi][ni][3];
      *(bf16x4*)(sh + (size_t)(c0 + ni * 16) * 264 + r0 + mi * 16) = pk;
    }
  __syncthreads();

  // ---- reduce over n: thread (nq 0..3, hl 0..1, d 0..63), 64 n's each, b128
  const int nq = tid >> 7, hl = (tid >> 6) & 1, d = tid & 63;
  const float* pw = p2 + (size_t)(h0 + hl) * 4096 + (m0 & 4095) + nq * 64;
  const bf16* pk = sh + (size_t)(hl * 128 + d) * 264 + nq * 64;
  const bf16* pv = sh + (size_t)(hl * 128 + 64 + d) * 264 + nq * 64;
  float s = 0.f;
#pragma unroll
  for (int nb = 0; nb < 8; ++nb) {
    const bf16x8 k8 = *(const bf16x8*)(pk + nb * 8);
    const bf16x8 v8 = *(const bf16x8*)(pv + nb * 8);
#pragma unroll
    for (int e = 0; e < 8; ++e)
      s += pw[nb * 8 + e] * (float)k8[e] * (float)v8[e];
  }
  red[nq][hl][d] = s;
  __syncthreads();
  if (tid < 128) {
    const int hx = tid >> 6, dd = tid & 63;
    partials[((size_t)mblk * 12 + h0 + hx) * 64 + dd] =
        red[0][hx][dd] + red[1][hx][dd] + red[2][hx][dd] + red[3][hx][dd];
  }
}

// ---------------------------------------------------------------------------
// Stage 2: sum the 16 per-mblk partials of each batch, then LayerNorm over d.
// grid (12 h, 8 b); 64 threads, d = lane.
// ---------------------------------------------------------------------------
__global__ __launch_bounds__(64) void mod_reduce_ln(const float* __restrict__ partials,
                                                    const float* __restrict__ gamma,
                                                    const float* __restrict__ beta,
                                                    float* __restrict__ mod) {
  const int h = blockIdx.x, b = blockIdx.y;
  const int d = threadIdx.x;

  const float* p = partials + ((size_t)(b * 16) * 12 + h) * 64 + d;
  float s = 0.f;
#pragma unroll
  for (int mb = 0; mb < 16; ++mb) s += p[(size_t)mb * 12 * 64];

  float sum = s, sumsq = s * s;
#pragma unroll
  for (int o = 32; o > 0; o >>= 1) {
    sum   += __shfl_xor(sum, o);
    sumsq += __shfl_xor(sumsq, o);
  }
  const float mu  = sum * (1.f / 64.f);
  const float var = sumsq * (1.f / 64.f) - mu * mu;
  const float r   = rsqrtf(var + LN_EPS);
  mod[(b * 12 + h) * 64 + d] = (s - mu) * r * gamma[d] + beta[d];
}

// ---------------------------------------------------------------------------
// Pass 2: q GEMM + fused modulation. Grid (3 nblk, 128 mblk).
// amod[m, c] = q[m, c] * p1[h(c), n(m)] * mod[b(m), c]  (bf16 out)
// ---------------------------------------------------------------------------
__global__ __launch_bounds__(512, 2) void q_gemm_mod(const bf16* __restrict__ A,
                                                     const bf16* __restrict__ B,
                                                     const float* __restrict__ p1,
                                                     const float* __restrict__ mod,
                                                     bf16* __restrict__ amod) {
  __shared__ __align__(16) bf16 sh[65536];

  int lin = blockIdx.y * 3 + blockIdx.x;       // 384 blocks, XCD-bijective swizzle
  lin = (lin & 7) * 48 + (lin >> 3);
  const int n0 = (lin % 3) * 256;
  const int m0 = (lin / 3) * 256;

  const int tid = threadIdx.x;
  const int rr  = tid >> 2;
  const int ck  = ((tid & 3) ^ ((tid >> 3) & 3)) * 8;
  const bf16* pA0 = A + (size_t)(m0 + rr) * 768 + ck;
  const bf16* pA1 = pA0 + (size_t)128 * 768;
  const bf16* pB0 = B + (size_t)(n0 + rr) * 768 + ck;
  const bf16* pB1 = pB0 + (size_t)128 * 768;

  f32x4 acc[8][4] = {};
  gemm256(pA0, pA1, pB0, pB1, sh, acc);

  const int lane = tid & 63, wave = tid >> 6;
  const int wm = wave >> 2, wn = wave & 3, l16 = lane & 15;
  const int row0 = m0 + wm * 128 + (lane >> 4) * 4;
  const int col0 = n0 + wn * 64 + l16;
  const int b    = m0 >> 12;
  const int h    = (n0 >> 6) + wn;             // wave-uniform head

  float p1v[8][4];
#pragma unroll
  for (int mi = 0; mi < 8; ++mi)
#pragma unroll
    for (int r = 0; r < 4; ++r)
      p1v[mi][r] = p1[(size_t)h * 4096 + ((row0 + mi * 16 + r) & 4095)];
  float mv[4];
#pragma unroll
  for (int ni = 0; ni < 4; ++ni) mv[ni] = mod[b * 768 + col0 + ni * 16];

#pragma unroll
  for (int mi = 0; mi < 8; ++mi)
#pragma unroll
    for (int ni = 0; ni < 4; ++ni)
#pragma unroll
      for (int r = 0; r < 4; ++r)
        amod[(size_t)(row0 + mi * 16 + r) * 768 + col0 + ni * 16] =
            (bf16)(acc[mi][ni][r] * p1v[mi][r] * mv[ni]);
}

// ---------------------------------------------------------------------------
// Pass 3: out[32768,768] fp32 = amod @ w_proj_bf16^T + b_proj. Grid (3, 128).
// ---------------------------------------------------------------------------
__global__ __launch_bounds__(512, 2) void gemm_proj(const bf16* __restrict__ A,
                                                    const bf16* __restrict__ B,
                                                    const float* __restrict__ bias,
                                                    float* __restrict__ C) {
  __shared__ __align__(16) bf16 sh[65536];

  int lin = blockIdx.y * 3 + blockIdx.x;
  lin = (lin & 7) * 48 + (lin >> 3);
  const int n0 = (lin % 3) * 256;
  const int m0 = (lin / 3) * 256;

  const int tid = threadIdx.x;
  const int rr  = tid >> 2;
  const int ck  = ((tid & 3) ^ ((tid >> 3) & 3)) * 8;
  const bf16* pA0 = A + (size_t)(m0 + rr) * 768 + ck;
  const bf16* pA1 = pA0 + (size_t)128 * 768;
  const bf16* pB0 = B + (size_t)(n0 + rr) * 768 + ck;
  const bf16* pB1 = pB0 + (size_t)128 * 768;

  f32x4 acc[8][4] = {};
  gemm256(pA0, pA1, pB0, pB1, sh, acc);

  const int lane = tid & 63, wave = tid >> 6;
  const int wm = wave >> 2, wn = wave & 3, l16 = lane & 15;
  const int row0 = m0 + wm * 128 + (lane >> 4) * 4;
  const int col0 = n0 + wn * 64 + l16;
#pragma unroll
  for (int ni = 0; ni < 4; ++ni) {
    const int col = col0 + ni * 16;
    const float bv = bias[col];
#pragma unroll
    for (int mi = 0; mi < 8; ++mi)
#pragma unroll
      for (int r = 0; r < 4; ++r)
        C[(size_t)(row0 + mi * 16 + r) * 768 + col] = acc[mi][ni][r] + bv;
  }
}

// ---------------------------------------------------------------------------
extern "C" void kernel_launch(void* const* d_in, const int* in_sizes, int n_in,
                              void* d_out, int out_size, void* d_ws, size_t ws_size,
                              hipStream_t stream) {
  (void)in_sizes; (void)n_in; (void)out_size; (void)ws_size;

  const float* x      = (const float*)d_in[0];   // [8,4096,768]
  const float* w_qkv  = (const float*)d_in[1];   // [2304,768]
  const float* w_proj = (const float*)d_in[2];   // [768,768]
  const float* b_proj = (const float*)d_in[3];   // [768]
  const float* p1     = (const float*)d_in[4];   // [12,4096]
  const float* p2     = (const float*)d_in[5];   // [12,4096]
  const float* gamma  = (const float*)d_in[6];   // [64]
  const float* beta   = (const float*)d_in[7];   // [64]
  float* out = (float*)d_out;                    // [8,4096,768] fp32

  char* ws = (char*)d_ws;
  bf16*  xb       = (bf16*)(ws + 0);              // 50,331,648  x bf16 [32768,768]
  bf16*  wqb      = (bf16*)(ws + 50331648);       //  3,538,944  w_qkv bf16
  bf16*  wpb      = (bf16*)(ws + 53870592);       //  1,179,648  w_proj bf16
  bf16*  amod     = (bf16*)(ws + 55050240);       // 50,331,648  amod bf16 [32768,768]
  float* partials = (float*)(ws + 105381888);     //    393,216  [128][12][64] f32
  float* mod      = (float*)(ws + 106168320);     //     24,576  [8][12][64] f32

  // 1) all fp32 -> bf16 conversions in one launch (26,880 blocks exact)
  cvt_all<<<26880, 256, 0, stream>>>(x, w_qkv, w_proj, xb, wqb, wpb);

  // 2) k/v GEMM + fused p2*k*v reduction (k,v never written to HBM)
  kv_gemm_reduce<<<dim3(6, 128), 512, 0, stream>>>(xb, wqb, p2, partials);

  // 3) finish reduction + LayerNorm -> mod [8,12,64]
  mod_reduce_ln<<<dim3(12, 8), 64, 0, stream>>>(partials, gamma, beta, mod);

  // 4) q GEMM + fused p1/mod modulation -> amod bf16
  q_gemm_mod<<<dim3(3, 128), 512, 0, stream>>>(xb, wqb, p1, mod, amod);

  // 5) proj GEMM + bias -> out fp32
  gemm_proj<<<dim3(3, 128), 512, 0, stream>>>(amod, wpb, b_proj, out);
}